// Round 3
// baseline (172.463 us; speedup 1.0000x reference)
//
#include <hip/hip_runtime.h>
#include <hip/hip_fp16.h>
#include <math.h>

#define B_ 128
#define N_ 512
#define C_ 128
#define W_ 128
#define LDSW 136  // padded row stride (halves); b128 reads land conflict-free per 8-lane group

typedef _Float16 f16;
typedef _Float16 f16x8 __attribute__((ext_vector_type(8)));
typedef _Float16 f16x4 __attribute__((ext_vector_type(4)));
typedef float f32x4 __attribute__((ext_vector_type(4)));

#define MFMA16(a, b, c) __builtin_amdgcn_mfma_f32_16x16x32_f16(a, b, c, 0, 0, 0)

#define LOG2E 1.44269504f
#define MASKF (-1e-6f * LOG2E)  // faithful -1e-6 fill, in log2 domain

// ---------------------------------------------------------------------------
// K0: coalesced transpose Wq/Wk/Wv (fp32 [C][W]) -> fp16 WT[w][c] via LDS
// ---------------------------------------------------------------------------
__global__ __launch_bounds__(256) void prep_w(const float* __restrict__ Wq,
                                              const float* __restrict__ Wk,
                                              const float* __restrict__ Wv,
                                              f16* __restrict__ wT) {
  __shared__ float xs[128 * 129];
  const float* src = blockIdx.x == 0 ? Wq : (blockIdx.x == 1 ? Wk : Wv);
  f16* dst = wT + (size_t)blockIdx.x * C_ * W_;
  const int t = threadIdx.x;
  for (int i = 0; i < 16; ++i) {
    int idx = t + 256 * i;          // 4096 float4
    int c = idx >> 5, w4 = idx & 31;
    float4 v = *reinterpret_cast<const float4*>(src + c * W_ + w4 * 4);
    xs[c * 129 + w4 * 4 + 0] = v.x;
    xs[c * 129 + w4 * 4 + 1] = v.y;
    xs[c * 129 + w4 * 4 + 2] = v.z;
    xs[c * 129 + w4 * 4 + 3] = v.w;
  }
  __syncthreads();
  for (int i = 0; i < 64; ++i) {
    int idx = t + 256 * i;          // 16384 elements
    int w = idx >> 7, c = idx & 127;
    dst[idx] = (f16)xs[c * 129 + w];  // banks (c+w)%32: 2-way, free
  }
}

// ---------------------------------------------------------------------------
// K1: fused QKV projection. q (pre-scaled by log2e), k row-major fp16
//     [b][n][w]; v transposed vT[b][w][n]. One WG = 128 rows, 4 waves x 32.
// ---------------------------------------------------------------------------
__global__ __launch_bounds__(256) void proj(const float* __restrict__ x,
                                            const float* __restrict__ bq,
                                            const float* __restrict__ bk,
                                            const float* __restrict__ bv,
                                            const f16* __restrict__ wT,
                                            f16* __restrict__ q,
                                            f16* __restrict__ k,
                                            f16* __restrict__ vT) {
  __shared__ f16 xs[128 * LDSW];
  __shared__ f16 wls[128 * LDSW];
  const int b = blockIdx.y, n0 = blockIdx.x * 128;
  const int t = threadIdx.x, wave = t >> 6, lane = t & 63;
  const int quad = lane >> 4, l15 = lane & 15;

  for (int i = 0; i < 16; ++i) {
    int idx = t + 256 * i;
    int row = idx >> 5, c4 = idx & 31;
    const float4 v = *reinterpret_cast<const float4*>(
        x + ((size_t)(b * N_ + n0 + row)) * C_ + c4 * 4);
    f16x4 h;
    h.x = (f16)v.x; h.y = (f16)v.y; h.z = (f16)v.z; h.w = (f16)v.w;
    *reinterpret_cast<f16x4*>(&xs[row * LDSW + c4 * 4]) = h;
  }
  __syncthreads();

  f16x8 af[2][4];
  for (int mt = 0; mt < 2; ++mt)
    for (int ks = 0; ks < 4; ++ks)
      af[mt][ks] = *reinterpret_cast<const f16x8*>(
          &xs[(wave * 32 + mt * 16 + l15) * LDSW + ks * 32 + quad * 8]);

  for (int ph = 0; ph < 3; ++ph) {
    __syncthreads();
    for (int i = 0; i < 8; ++i) {
      int idx = t + 256 * i;
      int row = idx >> 4, c16 = idx & 15;
      *reinterpret_cast<f16x8*>(&wls[row * LDSW + c16 * 8]) =
          *reinterpret_cast<const f16x8*>(wT + (size_t)ph * 16384 + idx * 8);
    }
    __syncthreads();

    f32x4 acc[2][8];
    for (int mt = 0; mt < 2; ++mt)
      for (int ct = 0; ct < 8; ++ct) acc[mt][ct] = {0.f, 0.f, 0.f, 0.f};

    for (int ct = 0; ct < 8; ++ct)
      for (int ks = 0; ks < 4; ++ks) {
        f16x8 bf = *reinterpret_cast<const f16x8*>(
            &wls[(ct * 16 + l15) * LDSW + ks * 32 + quad * 8]);
        acc[0][ct] = MFMA16(af[0][ks], bf, acc[0][ct]);
        acc[1][ct] = MFMA16(af[1][ks], bf, acc[1][ct]);
      }

    if (ph < 2) {
      const float* bias = ph == 0 ? bq : bk;
      const float scale = ph == 0 ? LOG2E : 1.0f;
      f16* dst = ph == 0 ? q : k;
      for (int mt = 0; mt < 2; ++mt)
        for (int ct = 0; ct < 8; ++ct) {
          int wcol = ct * 16 + l15;
          float bb = bias[wcol];
          for (int r = 0; r < 4; ++r) {
            int n = n0 + wave * 32 + mt * 16 + quad * 4 + r;
            dst[((size_t)(b * N_ + n)) * W_ + wcol] =
                (f16)((acc[mt][ct][r] + bb) * scale);
          }
        }
    } else {
      for (int mt = 0; mt < 2; ++mt)
        for (int ct = 0; ct < 8; ++ct) {
          int wcol = ct * 16 + l15;
          float bb = bv[wcol];
          int n = n0 + wave * 32 + mt * 16 + quad * 4;
          f16x4 h;
          h.x = (f16)(acc[mt][ct][0] + bb);
          h.y = (f16)(acc[mt][ct][1] + bb);
          h.z = (f16)(acc[mt][ct][2] + bb);
          h.w = (f16)(acc[mt][ct][3] + bb);
          *reinterpret_cast<f16x4*>(&vT[((size_t)(b * W_ + wcol)) * N_ + n]) = h;
        }
    }
  }
}

// ---------------------------------------------------------------------------
// K2: flash attention, wave-autonomous (ZERO __syncthreads).
//     Each wave owns 32 m-columns; per 128-key chunk it computes the full
//     S^T = K.Q^T slab for those columns (8 n-tiles), does wave-local online
//     softmax (log2 domain; q pre-scaled by log2e), round-trips P^T through
//     wave-private LDS rows, and accumulates O^T = V^T.P^T.
//     Faithful mask: key n > valid_len[b] -> score fill -1e-6 (participates).
// ---------------------------------------------------------------------------
__global__ __launch_bounds__(256, 2) void flash(const f16* __restrict__ q,
                                                const f16* __restrict__ k,
                                                const f16* __restrict__ vT,
                                                const int* __restrict__ vlen,
                                                float* __restrict__ out) {
  __shared__ f16 pls[128 * LDSW];
  const int b = blockIdx.x, m0 = blockIdx.y * 128;  // same-b WGs -> same XCD
  const int t = threadIdx.x, wave = t >> 6, lane = t & 63;
  const int quad = lane >> 4, l15 = lane & 15;
  const int vl = vlen[b];
  const int mcol = m0 + wave * 32;  // wave's m-range [mcol, mcol+32)

  // Q B-fragments, direct from global, held all kernel: qf[ct][kt]
  f16x8 qf[2][4];
  for (int ct = 0; ct < 2; ++ct)
    for (int kt = 0; kt < 4; ++kt)
      qf[ct][kt] = *reinterpret_cast<const f16x8*>(
          q + ((size_t)(b * N_ + mcol + ct * 16 + l15)) * W_ + kt * 32 +
          quad * 8);

  f32x4 oacc[8][2];  // [w-tile][ct]
  for (int wt = 0; wt < 8; ++wt)
    for (int ct = 0; ct < 2; ++ct) oacc[wt][ct] = {0.f, 0.f, 0.f, 0.f};
  float mrun[2] = {-3.4e38f, -3.4e38f}, lrun[2] = {0.f, 0.f};

  f16* prow = &pls[(size_t)wave * 32 * LDSW];  // wave-private 32 rows

  for (int j = 0; j < 4; ++j) {
    const int n0 = j * 128;

    // S^T slab: 8 n-tiles x 2 ct; K A-frags streamed per n-tile
    f32x4 sacc[8][2];
    for (int i = 0; i < 8; ++i) {
      sacc[i][0] = {0.f, 0.f, 0.f, 0.f};
      sacc[i][1] = {0.f, 0.f, 0.f, 0.f};
      f16x8 kf[4];
      for (int kt = 0; kt < 4; ++kt)
        kf[kt] = *reinterpret_cast<const f16x8*>(
            k + ((size_t)(b * N_ + n0 + 16 * i + l15)) * W_ + kt * 32 +
            quad * 8);
      for (int kt = 0; kt < 4; ++kt) {
        sacc[i][0] = MFMA16(kf[kt], qf[0][kt], sacc[i][0]);
        sacc[i][1] = MFMA16(kf[kt], qf[1][kt], sacc[i][1]);
      }
    }

    // mask: n = n0 + 16i + quad*4 + r
    for (int i = 0; i < 8; ++i)
      for (int r = 0; r < 4; ++r) {
        int n = n0 + 16 * i + quad * 4 + r;
        if (n > vl) { sacc[i][0][r] = MASKF; sacc[i][1][r] = MASKF; }
      }

    // wave-local online softmax per ct (stats replicated across quads)
    float alpha[2];
    for (int ct = 0; ct < 2; ++ct) {
      float mx = -3.4e38f;
      for (int i = 0; i < 8; ++i)
        for (int r = 0; r < 4; ++r) mx = fmaxf(mx, sacc[i][ct][r]);
      mx = fmaxf(mx, __shfl_xor(mx, 16));
      mx = fmaxf(mx, __shfl_xor(mx, 32));
      float mnew = fmaxf(mrun[ct], mx);
      alpha[ct] = exp2f(mrun[ct] - mnew);
      mrun[ct] = mnew;
      float s = 0.f;
      for (int i = 0; i < 8; ++i)
        for (int r = 0; r < 4; ++r) {
          float p = exp2f(sacc[i][ct][r] - mnew);
          sacc[i][ct][r] = p;
          s += p;
        }
      s += __shfl_xor(s, 16);
      s += __shfl_xor(s, 32);
      lrun[ct] = lrun[ct] * alpha[ct] + s;
    }

    // P^T -> wave-private LDS rows (b64 writes; no barrier needed)
    for (int i = 0; i < 8; ++i)
      for (int ct = 0; ct < 2; ++ct) {
        f16x4 h;
        h.x = (f16)sacc[i][ct][0];
        h.y = (f16)sacc[i][ct][1];
        h.z = (f16)sacc[i][ct][2];
        h.w = (f16)sacc[i][ct][3];
        *reinterpret_cast<f16x4*>(
            &prow[(ct * 16 + l15) * LDSW + 16 * i + quad * 4]) = h;
      }

    // rescale O
    for (int wt = 0; wt < 8; ++wt) {
      oacc[wt][0] *= alpha[0];
      oacc[wt][1] *= alpha[1];
    }

    // P^T B-fragments back from LDS (b128, same-wave dependency)
    f16x8 pf[2][4];
    for (int ct = 0; ct < 2; ++ct)
      for (int kt = 0; kt < 4; ++kt)
        pf[ct][kt] = *reinterpret_cast<const f16x8*>(
            &prow[(ct * 16 + l15) * LDSW + kt * 32 + quad * 8]);

    // O^T += V^T . P^T ; V A-frags streamed per w-tile
    for (int wt = 0; wt < 8; ++wt) {
      f16x8 vf[4];
      for (int kt = 0; kt < 4; ++kt)
        vf[kt] = *reinterpret_cast<const f16x8*>(
            vT + ((size_t)(b * W_ + 16 * wt + l15)) * N_ + n0 + kt * 32 +
            quad * 8);
      for (int kt = 0; kt < 4; ++kt) {
        oacc[wt][0] = MFMA16(vf[kt], pf[0][kt], oacc[wt][0]);
        oacc[wt][1] = MFMA16(vf[kt], pf[1][kt], oacc[wt][1]);
      }
    }
  }

  // epilogue: O[m][w] = oacc / lrun  (4 consecutive w per reg quad)
  for (int ct = 0; ct < 2; ++ct) {
    float inv = 1.f / lrun[ct];
    int m = mcol + ct * 16 + l15;
    for (int wt = 0; wt < 8; ++wt) {
      int w = 16 * wt + quad * 4;
      float4 o;
      o.x = oacc[wt][ct][0] * inv;
      o.y = oacc[wt][ct][1] * inv;
      o.z = oacc[wt][ct][2] * inv;
      o.w = oacc[wt][ct][3] * inv;
      *reinterpret_cast<float4*>(&out[((size_t)(b * N_ + m)) * W_ + w]) = o;
    }
  }
}

// ---------------------------------------------------------------------------
extern "C" void kernel_launch(void* const* d_in, const int* in_sizes, int n_in,
                              void* d_out, int out_size, void* d_ws,
                              size_t ws_size, hipStream_t stream) {
  const float* x  = (const float*)d_in[0];
  const float* Wq = (const float*)d_in[1];
  const float* bq = (const float*)d_in[2];
  const float* Wk = (const float*)d_in[3];
  const float* bk = (const float*)d_in[4];
  const float* Wv = (const float*)d_in[5];
  const float* bv = (const float*)d_in[6];
  const int* vlen = (const int*)d_in[7];
  float* out = (float*)d_out;

  char* ws = (char*)d_ws;
  f16* wT = (f16*)ws;
  f16* q  = (f16*)(ws + (1u << 20));
  f16* k  = (f16*)(ws + (1u << 20) + (16u << 20));
  f16* vT = (f16*)(ws + (1u << 20) + (32u << 20));

  prep_w<<<3, 256, 0, stream>>>(Wq, Wk, Wv, wT);
  proj<<<dim3(4, 128), 256, 0, stream>>>(x, bq, bk, bv, wT, q, k, vT);
  flash<<<dim3(128, 4), 256, 0, stream>>>(q, k, vT, vlen, out);
}

// Round 4
// 157.324 us; speedup vs baseline: 1.0962x; 1.0962x over previous
//
#include <hip/hip_runtime.h>
#include <hip/hip_fp16.h>
#include <math.h>

#define B_ 128
#define N_ 512
#define C_ 128
#define W_ 128
#define LDSW 136  // padded row stride (halves); b128 access = uniform bank spread (8-cyc floor)

typedef _Float16 f16;
typedef _Float16 f16x8 __attribute__((ext_vector_type(8)));
typedef _Float16 f16x4 __attribute__((ext_vector_type(4)));
typedef float f32x4 __attribute__((ext_vector_type(4)));

#define MFMA16(a, b, c) __builtin_amdgcn_mfma_f32_16x16x32_f16(a, b, c, 0, 0, 0)

#define LOG2E 1.44269504f
#define MASKF (-1e-6f * LOG2E)  // faithful -1e-6 fill, log2 domain

// ---------------------------------------------------------------------------
// K0: transpose Wq/Wk/Wv (fp32 [C][W]) -> fp16 WT[w][c]. grid(3 mats, 8 slabs)
// ---------------------------------------------------------------------------
__global__ __launch_bounds__(256) void prep_w(const float* __restrict__ Wq,
                                              const float* __restrict__ Wk,
                                              const float* __restrict__ Wv,
                                              f16* __restrict__ wT) {
  __shared__ float xs[16 * 129];
  const float* src = blockIdx.x == 0 ? Wq : (blockIdx.x == 1 ? Wk : Wv);
  f16* dst = wT + (size_t)blockIdx.x * C_ * W_;
  const int c0 = blockIdx.y * 16;
  const int t = threadIdx.x;
  for (int ii = 0; ii < 2; ++ii) {
    int idx = t + 256 * ii;           // 512 float4 = 16 rows x 32
    int row = idx >> 5, w4 = idx & 31;
    float4 v = *reinterpret_cast<const float4*>(src + (c0 + row) * W_ + w4 * 4);
    xs[row * 129 + w4 * 4 + 0] = v.x;
    xs[row * 129 + w4 * 4 + 1] = v.y;
    xs[row * 129 + w4 * 4 + 2] = v.z;
    xs[row * 129 + w4 * 4 + 3] = v.w;
  }
  __syncthreads();
  int o = t * 8;
  int w = o >> 4, cc = o & 15;        // cc in {0,8}
  f16x8 h;
  for (int jj = 0; jj < 8; ++jj) h[jj] = (f16)xs[(cc + jj) * 129 + w];
  *reinterpret_cast<f16x8*>(dst + w * C_ + c0 + cc) = h;
}

// ---------------------------------------------------------------------------
// K1: fused QKV projection, ONE barrier. Weight B-frags direct from global
//     (same addresses across all waves/WGs -> L1/L2 broadcast). q pre-scaled
//     by log2e; q,k row-major [b][n][w]; v transposed vT[b][w][n].
// ---------------------------------------------------------------------------
__global__ __launch_bounds__(256) void proj(const float* __restrict__ x,
                                            const float* __restrict__ bq,
                                            const float* __restrict__ bk,
                                            const float* __restrict__ bv,
                                            const f16* __restrict__ wT,
                                            f16* __restrict__ q,
                                            f16* __restrict__ k,
                                            f16* __restrict__ vT) {
  __shared__ f16 xs[128 * LDSW];
  const int b = blockIdx.y, n0 = blockIdx.x * 128;
  const int t = threadIdx.x, wave = t >> 6, lane = t & 63;
  const int quad = lane >> 4, l15 = lane & 15;

  for (int i = 0; i < 16; ++i) {
    int idx = t + 256 * i;
    int row = idx >> 5, c4 = idx & 31;
    const float4 v = *reinterpret_cast<const float4*>(
        x + ((size_t)(b * N_ + n0 + row)) * C_ + c4 * 4);
    f16x4 h;
    h.x = (f16)v.x; h.y = (f16)v.y; h.z = (f16)v.z; h.w = (f16)v.w;
    *reinterpret_cast<f16x4*>(&xs[row * LDSW + c4 * 4]) = h;
  }
  __syncthreads();

  f16x8 af[2][4];
  for (int mt = 0; mt < 2; ++mt)
    for (int ks = 0; ks < 4; ++ks)
      af[mt][ks] = *reinterpret_cast<const f16x8*>(
          &xs[(wave * 32 + mt * 16 + l15) * LDSW + ks * 32 + quad * 8]);

  for (int ph = 0; ph < 3; ++ph) {
    f32x4 acc[2][8];
    for (int mt = 0; mt < 2; ++mt)
      for (int ct = 0; ct < 8; ++ct) acc[mt][ct] = {0.f, 0.f, 0.f, 0.f};

    for (int ct = 0; ct < 8; ++ct) {
      f16x8 wf[4];
      for (int ks = 0; ks < 4; ++ks)
        wf[ks] = *reinterpret_cast<const f16x8*>(
            wT + (size_t)ph * 16384 + (ct * 16 + l15) * C_ + ks * 32 +
            quad * 8);
      for (int ks = 0; ks < 4; ++ks) {
        acc[0][ct] = MFMA16(af[0][ks], wf[ks], acc[0][ct]);
        acc[1][ct] = MFMA16(af[1][ks], wf[ks], acc[1][ct]);
      }
    }

    if (ph < 2) {
      const float* bias = ph == 0 ? bq : bk;
      const float scale = ph == 0 ? LOG2E : 1.0f;
      f16* dst = ph == 0 ? q : k;
      for (int mt = 0; mt < 2; ++mt)
        for (int ct = 0; ct < 8; ++ct) {
          int wcol = ct * 16 + l15;
          float bb = bias[wcol];
          for (int r = 0; r < 4; ++r) {
            int n = n0 + wave * 32 + mt * 16 + quad * 4 + r;
            dst[((size_t)(b * N_ + n)) * W_ + wcol] =
                (f16)((acc[mt][ct][r] + bb) * scale);
          }
        }
    } else {
      for (int mt = 0; mt < 2; ++mt)
        for (int ct = 0; ct < 8; ++ct) {
          int wcol = ct * 16 + l15;
          float bb = bv[wcol];
          int n = n0 + wave * 32 + mt * 16 + quad * 4;
          f16x4 h;
          h.x = (f16)(acc[mt][ct][0] + bb);
          h.y = (f16)(acc[mt][ct][1] + bb);
          h.z = (f16)(acc[mt][ct][2] + bb);
          h.w = (f16)(acc[mt][ct][3] + bb);
          *reinterpret_cast<f16x4*>(&vT[((size_t)(b * W_ + wcol)) * N_ + n]) = h;
        }
    }
  }
}

// ---------------------------------------------------------------------------
// K2: flash v4. Per 128-key chunk:
//   stage K->LDS (coop) | bar | QK m-split (wave-local online softmax)
//   | write P^T slab + alpha bcast | bar | PV w-split (V direct, 8 b128/wave)
// Faithful mask: key n > valid_len[b] -> fill -1e-6 (participates in softmax).
// ---------------------------------------------------------------------------
__global__ __launch_bounds__(256, 2) void flash(const f16* __restrict__ q,
                                                const f16* __restrict__ k,
                                                const f16* __restrict__ vT,
                                                const int* __restrict__ vlen,
                                                float* __restrict__ out) {
  __shared__ f16 kls[128 * LDSW];
  __shared__ f16 pls[128 * LDSW];
  __shared__ float bcast[128];
  const int b = blockIdx.x, m0 = blockIdx.y * 128;  // same-b WGs -> same XCD
  const int t = threadIdx.x, wave = t >> 6, lane = t & 63;
  const int quad = lane >> 4, l15 = lane & 15;
  const int vl = vlen[b];
  const int mcol = m0 + wave * 32;

  // Q B-frags for this wave's 32 m-cols, held all kernel
  f16x8 qf[2][4];
  for (int ct = 0; ct < 2; ++ct)
    for (int kt = 0; kt < 4; ++kt)
      qf[ct][kt] = *reinterpret_cast<const f16x8*>(
          q + ((size_t)(b * N_ + mcol + ct * 16 + l15)) * W_ + kt * 32 +
          quad * 8);

  f32x4 oacc[2][8];  // [wt (this wave's w)][cm (all 128 m)]
  for (int wt = 0; wt < 2; ++wt)
    for (int cm = 0; cm < 8; ++cm) oacc[wt][cm] = {0.f, 0.f, 0.f, 0.f};
  float mrun[2] = {-3.4e38f, -3.4e38f}, lrun[2] = {0.f, 0.f};

  for (int j = 0; j < 4; ++j) {
    const int n0 = j * 128;

    // cooperative K-chunk staging (32 KB)
    for (int i = 0; i < 8; ++i) {
      int idx = t + 256 * i;
      int row = idx >> 4, c16 = idx & 15;
      f16x8 tmp = *reinterpret_cast<const f16x8*>(
          k + ((size_t)(b * N_ + n0 + row)) * W_ + c16 * 8);
      *reinterpret_cast<f16x8*>(&kls[row * LDSW + c16 * 8]) = tmp;
    }
    __syncthreads();  // bar1: K visible; PV(j-1)'s pls reads all done

    // QK: S^T slab (128 n x wave's 32 m)
    f32x4 sacc[8][2];
    for (int i = 0; i < 8; ++i) {
      sacc[i][0] = {0.f, 0.f, 0.f, 0.f};
      sacc[i][1] = {0.f, 0.f, 0.f, 0.f};
      f16x8 kf[4];
      for (int kt = 0; kt < 4; ++kt)
        kf[kt] = *reinterpret_cast<const f16x8*>(
            &kls[(i * 16 + l15) * LDSW + kt * 32 + quad * 8]);
      for (int kt = 0; kt < 4; ++kt) {
        sacc[i][0] = MFMA16(kf[kt], qf[0][kt], sacc[i][0]);
        sacc[i][1] = MFMA16(kf[kt], qf[1][kt], sacc[i][1]);
      }
    }

    // mask (key index n = S^T row)
    for (int i = 0; i < 8; ++i)
      for (int r = 0; r < 4; ++r) {
        int n = n0 + 16 * i + quad * 4 + r;
        if (n > vl) { sacc[i][0][r] = MASKF; sacc[i][1][r] = MASKF; }
      }

    // wave-local online softmax (stats replicated across quads)
    float alpha[2];
    for (int ct = 0; ct < 2; ++ct) {
      float mx = -3.4e38f;
      for (int i = 0; i < 8; ++i)
        for (int r = 0; r < 4; ++r) mx = fmaxf(mx, sacc[i][ct][r]);
      mx = fmaxf(mx, __shfl_xor(mx, 16));
      mx = fmaxf(mx, __shfl_xor(mx, 32));
      float mnew = fmaxf(mrun[ct], mx);
      alpha[ct] = exp2f(mrun[ct] - mnew);
      mrun[ct] = mnew;
      float s = 0.f;
      for (int i = 0; i < 8; ++i)
        for (int r = 0; r < 4; ++r) {
          float p = exp2f(sacc[i][ct][r] - mnew);
          sacc[i][ct][r] = p;
          s += p;
        }
      s += __shfl_xor(s, 16);
      s += __shfl_xor(s, 32);
      lrun[ct] = lrun[ct] * alpha[ct] + s;
    }

    // write P^T slab (wave-own 32 m rows x 128 n) + alpha broadcast
    for (int i = 0; i < 8; ++i)
      for (int ct = 0; ct < 2; ++ct) {
        f16x4 h;
        h.x = (f16)sacc[i][ct][0];
        h.y = (f16)sacc[i][ct][1];
        h.z = (f16)sacc[i][ct][2];
        h.w = (f16)sacc[i][ct][3];
        *reinterpret_cast<f16x4*>(
            &pls[(wave * 32 + ct * 16 + l15) * LDSW + 16 * i + quad * 4]) = h;
      }
    if (quad == 0) {
      bcast[wave * 32 + l15] = alpha[0];
      bcast[wave * 32 + 16 + l15] = alpha[1];
    }

    // V^T A-frags for this wave's w-slab (global; issued across bar2)
    f16x8 vf[2][4];
    for (int wt = 0; wt < 2; ++wt)
      for (int kt = 0; kt < 4; ++kt)
        vf[wt][kt] = *reinterpret_cast<const f16x8*>(
            vT + ((size_t)(b * W_ + wave * 32 + wt * 16 + l15)) * N_ + n0 +
            kt * 32 + quad * 8);
    __syncthreads();  // bar2: pls + bcast visible

    // rescale O by alpha of each m-col, then PV over all 128 m
    float al[8];
    for (int cm = 0; cm < 8; ++cm) al[cm] = bcast[cm * 16 + l15];
    for (int wt = 0; wt < 2; ++wt)
      for (int cm = 0; cm < 8; ++cm) oacc[wt][cm] *= al[cm];
    for (int cm = 0; cm < 8; ++cm) {
      f16x8 pf[4];
      for (int kt = 0; kt < 4; ++kt)
        pf[kt] = *reinterpret_cast<const f16x8*>(
            &pls[(cm * 16 + l15) * LDSW + kt * 32 + quad * 8]);
      for (int kt = 0; kt < 4; ++kt) {
        oacc[0][cm] = MFMA16(vf[0][kt], pf[kt], oacc[0][cm]);
        oacc[1][cm] = MFMA16(vf[1][kt], pf[kt], oacc[1][cm]);
      }
    }
  }

  // epilogue: broadcast 1/l, scale, store O[m][w] (float4, w contiguous)
  __syncthreads();  // all alpha reads of bcast done
  if (quad == 0) {
    bcast[wave * 32 + l15] = 1.f / lrun[0];
    bcast[wave * 32 + 16 + l15] = 1.f / lrun[1];
  }
  __syncthreads();
  for (int cm = 0; cm < 8; ++cm) {
    float inv = bcast[cm * 16 + l15];
    int m = m0 + cm * 16 + l15;
    for (int wt = 0; wt < 2; ++wt) {
      int w = wave * 32 + wt * 16 + quad * 4;
      float4 o;
      o.x = oacc[wt][cm][0] * inv;
      o.y = oacc[wt][cm][1] * inv;
      o.z = oacc[wt][cm][2] * inv;
      o.w = oacc[wt][cm][3] * inv;
      *reinterpret_cast<float4*>(&out[((size_t)(b * N_ + m)) * W_ + w]) = o;
    }
  }
}

// ---------------------------------------------------------------------------
extern "C" void kernel_launch(void* const* d_in, const int* in_sizes, int n_in,
                              void* d_out, int out_size, void* d_ws,
                              size_t ws_size, hipStream_t stream) {
  const float* x  = (const float*)d_in[0];
  const float* Wq = (const float*)d_in[1];
  const float* bq = (const float*)d_in[2];
  const float* Wk = (const float*)d_in[3];
  const float* bk = (const float*)d_in[4];
  const float* Wv = (const float*)d_in[5];
  const float* bv = (const float*)d_in[6];
  const int* vlen = (const int*)d_in[7];
  float* out = (float*)d_out;

  char* ws = (char*)d_ws;
  f16* wT = (f16*)ws;
  f16* q  = (f16*)(ws + (1u << 20));
  f16* k  = (f16*)(ws + (1u << 20) + (16u << 20));
  f16* vT = (f16*)(ws + (1u << 20) + (32u << 20));

  prep_w<<<dim3(3, 8), 256, 0, stream>>>(Wq, Wk, Wv, wT);
  proj<<<dim3(4, 128), 256, 0, stream>>>(x, bq, bk, bv, wT, q, k, vT);
  flash<<<dim3(128, 4), 256, 0, stream>>>(q, k, vT, vlen, out);
}